// Round 5
// baseline (239.637 us; speedup 1.0000x reference)
//
#include <hip/hip_runtime.h>
#include <hip/hip_bf16.h>

// 2-NN: out[q] = sum of 2 smallest ||q - t||^2 over 200000 train points.
// d2 = q_sq + t_sq - 2*q.t ; top-2 depends only on s = t_sq - 2*q.t.
// v5: queries pre-scaled by -2 (exact in bf16), t_sq injected via MFMA C-in
//     -> s = acc[r] directly, top-2 = min+med3 only.
//     3-deep LDS ring + raw s_barrier + counted vmcnt(2) (no per-iter drain).
//     XCD-grouped block remap: all 8 qblocks of a chunk on one XCD (L2-resident).

typedef short bf16x8 __attribute__((ext_vector_type(8)));   // 8 bf16 = 4 VGPRs
typedef float f32x4 __attribute__((ext_vector_type(4)));

#define N_TRAIN 200000
#define M_QUERY 2048
#define DIMS 128
#define TB 32                     // train points per pipeline tile (8 KB)

__device__ __forceinline__ unsigned int bf_bits(float f) {
  unsigned int u = __float_as_uint(f);
  return (u + 0x7FFFu + ((u >> 16) & 1u)) >> 16;
}

// 8 lanes per row; each lane handles 16 contiguous floats (64B) -> coalesced.
// dst holds bf16(scale * src); sq holds exact fp32 ||row||^2 of UNSCALED src.
__global__ __launch_bounds__(256) void convert_kernel(
    const float* __restrict__ src, unsigned short* __restrict__ dst,
    float* __restrict__ sq, int nrows, float scale) {
  int gtid = blockIdx.x * 256 + threadIdx.x;
  int row = gtid >> 3, sub = gtid & 7;
  if (row >= nrows) return;
  const float4* s4 = reinterpret_cast<const float4*>(src + (size_t)row * DIMS + sub * 16);
  unsigned int pk[8];
  float acc = 0.f;
#pragma unroll
  for (int i = 0; i < 4; ++i) {
    float4 v = s4[i];
    acc += v.x * v.x + v.y * v.y + v.z * v.z + v.w * v.w;
    pk[i * 2 + 0] = bf_bits(v.x * scale) | (bf_bits(v.y * scale) << 16);
    pk[i * 2 + 1] = bf_bits(v.z * scale) | (bf_bits(v.w * scale) << 16);
  }
  uint4* d4 = reinterpret_cast<uint4*>(dst + (size_t)row * DIMS + sub * 16);
  d4[0] = make_uint4(pk[0], pk[1], pk[2], pk[3]);
  d4[1] = make_uint4(pk[4], pk[5], pk[6], pk[7]);
  acc += __shfl_xor(acc, 1);
  acc += __shfl_xor(acc, 2);
  acc += __shfl_xor(acc, 4);
  if (sub == 0) sq[row] = acc;
}

// Main. Block = 4 waves; wave owns 64 queries (4 m-tiles of 16).
// Block remap: xcd = b&7 (HW round-robin), all 8 qblocks of a chunk on ONE xcd.
template <int NCH>
__global__ __launch_bounds__(256) void knn_main(
    const unsigned short* __restrict__ tb, const unsigned short* __restrict__ qb16,
    const float* __restrict__ tsq, float* __restrict__ partials) {
  constexpr int PPC = N_TRAIN / NCH;
  constexpr int ITERS = PPC / TB;
  const int b = blockIdx.x;
  const int g = (b & 7) * NCH + (b >> 3);   // same-xcd blocks get consecutive g
  const int chunk = g >> 3;
  const int qblock = (g & 7) << 8;
  const int tid = threadIdx.x;
  const int w = tid >> 6, l = tid & 63;
  const int lo = l & 15, hi = l >> 4;
  const int qw = qblock + w * 64;

  __shared__ char smem[3 * 8192];           // 3-tile ring
  __shared__ float tsq_s[PPC];

  // A-fragments (hold -2*q in bf16): Q[qw + t*16 + lo][kf*32 + hi*8 .. +8]
  bf16x8 a[4][4];
#pragma unroll
  for (int t = 0; t < 4; ++t)
#pragma unroll
    for (int kf = 0; kf < 4; ++kf)
      a[t][kf] = *reinterpret_cast<const bf16x8*>(
          qb16 + (size_t)(qw + t * 16 + lo) * DIMS + kf * 32 + hi * 8);

  // t_sq chunk into LDS (before gll issues so its vmem drains first)
  for (int i = tid; i < PPC; i += 256) tsq_s[i] = tsq[chunk * PPC + i];
  __builtin_amdgcn_sched_barrier(0);

  // gll: LDS dest linear (wave base + lane*16); global source pre-swizzled so
  // LDS[(row, blk)] = global(row, blk ^ (row&7)).  (verified layout, r2-r4)
  const int srow = tid >> 4, sblk = tid & 15;
  const char* gsrc = reinterpret_cast<const char*>(tb) +
                     (size_t)chunk * PPC * 256 + srow * 256 + ((sblk ^ (srow & 7)) << 4);

  // ds_read offsets: point p = 16*half + lo, block kb = kf*4+hi:
  // addr = p*256 + ((kb ^ (p&7)) << 4); +4096 for the upper half.
  int roff[4];
#pragma unroll
  for (int kf = 0; kf < 4; ++kf)
    roff[kf] = lo * 256 + ((((kf << 2) + hi) ^ (lo & 7)) << 4);

  const float INF = __builtin_inff();
  float best1[4][4], best2[4][4];
#pragma unroll
  for (int t = 0; t < 4; ++t)
#pragma unroll
    for (int r = 0; r < 4; ++r) { best1[t][r] = INF; best2[t][r] = INF; }

  // prologue: stage tiles 0,1 into ring bufs 0,1
#pragma unroll
  for (int p = 0; p < 2; ++p) {
    char* lb = smem + p * 8192 + w * 1024;
    __builtin_amdgcn_global_load_lds(
        (const __attribute__((address_space(1))) void*)gsrc,
        (__attribute__((address_space(3))) void*)lb, 16, 0, 0);
    __builtin_amdgcn_global_load_lds(
        (const __attribute__((address_space(1))) void*)(gsrc + 4096),
        (__attribute__((address_space(3))) void*)(lb + 4096), 16, 0, 0);
    gsrc += 8192;
  }
  // own slices of tile 0 landed (<=2 outstanding = tile 1) + tsq ds_writes done
  asm volatile("s_waitcnt vmcnt(2) lgkmcnt(0)" ::: "memory");

  int cur = 0, nxt = 2;
  for (int it = 0; it < ITERS; ++it) {
    __builtin_amdgcn_s_barrier();           // all waves: tile `it` visible
    __builtin_amdgcn_sched_barrier(0);

    if (it + 2 < ITERS) {  // issue tile it+2 into buf[nxt] (read finished @ it-1)
      char* nb = smem + (nxt << 13) + w * 1024;
      __builtin_amdgcn_global_load_lds(
          (const __attribute__((address_space(1))) void*)gsrc,
          (__attribute__((address_space(3))) void*)nb, 16, 0, 0);
      __builtin_amdgcn_global_load_lds(
          (const __attribute__((address_space(1))) void*)(gsrc + 4096),
          (__attribute__((address_space(3))) void*)(nb + 4096), 16, 0, 0);
      gsrc += 8192;
    }

    const char* buf = smem + (cur << 13);
    bf16x8 f0[4], f1[4];
#pragma unroll
    for (int kf = 0; kf < 4; ++kf) {
      f0[kf] = *reinterpret_cast<const bf16x8*>(buf + roff[kf]);
      f1[kf] = *reinterpret_cast<const bf16x8*>(buf + roff[kf] + 4096);
    }
    float tv0 = tsq_s[it * TB + lo];
    float tv1 = tsq_s[it * TB + 16 + lo];
    f32x4 c0 = {tv0, tv0, tv0, tv0};
    f32x4 c1 = {tv1, tv1, tv1, tv1};

    __builtin_amdgcn_s_setprio(1);
#pragma unroll
    for (int t = 0; t < 4; ++t) {
      f32x4 acc0 = __builtin_amdgcn_mfma_f32_16x16x32_bf16(a[t][0], f0[0], c0, 0, 0, 0);
      f32x4 acc1 = __builtin_amdgcn_mfma_f32_16x16x32_bf16(a[t][0], f1[0], c1, 0, 0, 0);
#pragma unroll
      for (int kf = 1; kf < 4; ++kf) {
        acc0 = __builtin_amdgcn_mfma_f32_16x16x32_bf16(a[t][kf], f0[kf], acc0, 0, 0, 0);
        acc1 = __builtin_amdgcn_mfma_f32_16x16x32_bf16(a[t][kf], f1[kf], acc1, 0, 0, 0);
      }
#pragma unroll
      for (int r = 0; r < 4; ++r) {
        float s0 = acc0[r];                 // = t_sq - 2 q.t  (C-in carried t_sq)
        float n1 = fminf(best1[t][r], s0);
        float n2 = __builtin_amdgcn_fmed3f(best1[t][r], best2[t][r], s0);
        best1[t][r] = n1; best2[t][r] = n2;
        float s1 = acc1[r];
        n1 = fminf(best1[t][r], s1);
        n2 = __builtin_amdgcn_fmed3f(best1[t][r], best2[t][r], s1);
        best1[t][r] = n1; best2[t][r] = n2;
      }
    }
    __builtin_amdgcn_s_setprio(0);

    if (it + 2 < ITERS) {
      asm volatile("s_waitcnt vmcnt(2)" ::: "memory");  // tile it+1 landed
    } else if (it + 2 == ITERS) {
      asm volatile("s_waitcnt vmcnt(0)" ::: "memory");  // last tile landed
    }
    cur = (cur == 2) ? 0 : cur + 1;
    nxt = (nxt == 2) ? 0 : nxt + 1;
  }

  // merge top-2 across the 16 lanes (columns) sharing each query
#pragma unroll
  for (int t = 0; t < 4; ++t)
#pragma unroll
    for (int r = 0; r < 4; ++r) {
      float v1 = best1[t][r], v2 = best2[t][r];
#pragma unroll
      for (int m = 1; m < 16; m <<= 1) {
        float o1 = __shfl_xor(v1, m);
        float o2 = __shfl_xor(v2, m);
        float n1 = fminf(v1, o1);
        float n2 = fminf(fmaxf(v1, o1), fminf(v2, o2));
        v1 = n1;
        v2 = n2;
      }
      best1[t][r] = v1;
      best2[t][r] = v2;
    }
  if (lo == 0) {
#pragma unroll
    for (int t = 0; t < 4; ++t)
#pragma unroll
      for (int r = 0; r < 4; ++r) {
        int q = qw + t * 16 + hi * 4 + r;
        float* p = partials + ((size_t)chunk * M_QUERY + q) * 2;
        p[0] = best1[t][r];
        p[1] = best2[t][r];
      }
  }
}

__global__ __launch_bounds__(256) void knn_reduce(
    const float* __restrict__ partials, const float* __restrict__ qsq,
    float* __restrict__ out, int nchunk) {
  int q = blockIdx.x * 256 + threadIdx.x;
  if (q >= M_QUERY) return;
  const float INF = __builtin_inff();
  float b1 = INF, b2 = INF;
  for (int c = 0; c < nchunk; ++c) {
    const float* p = partials + ((size_t)c * M_QUERY + q) * 2;
    float v = p[0];
    float n1 = fminf(b1, v);
    float n2 = __builtin_amdgcn_fmed3f(b1, b2, v);
    b1 = n1; b2 = n2;
    v = p[1];
    n1 = fminf(b1, v);
    n2 = __builtin_amdgcn_fmed3f(b1, b2, v);
    b1 = n1; b2 = n2;
  }
  out[q] = 2.f * qsq[q] + b1 + b2;
}

extern "C" void kernel_launch(void* const* d_in, const int* in_sizes, int n_in,
                              void* d_out, int out_size, void* d_ws, size_t ws_size,
                              hipStream_t stream) {
  const float* train = (const float*)d_in[0];  // 200000 x 128 f32
  const float* test  = (const float*)d_in[1];  // 2048 x 128 f32
  float* out = (float*)d_out;                  // 2048 f32
  char* ws = (char*)d_ws;

  size_t off_tb  = 0;                                      // train bf16: 51,200,000 B
  size_t off_qb  = off_tb  + (size_t)N_TRAIN * DIMS * 2;   // query bf16 (-2q)
  size_t off_tsq = off_qb  + (size_t)M_QUERY * DIMS * 2;   // t_sq
  size_t off_qsq = off_tsq + (size_t)N_TRAIN * 4;          // q_sq
  size_t off_pt  = off_qsq + (size_t)M_QUERY * 4;          // partials
  size_t need250 = off_pt + (size_t)250 * M_QUERY * 2 * 4;
  size_t need125 = off_pt + (size_t)125 * M_QUERY * 2 * 4;
  if (ws_size < need125) return;
  const bool use250 = (ws_size >= need250);

  unsigned short* tbp = (unsigned short*)(ws + off_tb);
  unsigned short* qb  = (unsigned short*)(ws + off_qb);
  float* tsq = (float*)(ws + off_tsq);
  float* qsq = (float*)(ws + off_qsq);
  float* part = (float*)(ws + off_pt);

  hipLaunchKernelGGL(convert_kernel, dim3((N_TRAIN * 8) / 256), dim3(256), 0, stream,
                     train, tbp, tsq, N_TRAIN, 1.0f);
  hipLaunchKernelGGL(convert_kernel, dim3((M_QUERY * 8) / 256), dim3(256), 0, stream,
                     test, qb, qsq, M_QUERY, -2.0f);
  if (use250) {
    hipLaunchKernelGGL(knn_main<250>, dim3(250 * 8), dim3(256), 0, stream,
                       tbp, qb, tsq, part);
    hipLaunchKernelGGL(knn_reduce, dim3(M_QUERY / 256), dim3(256), 0, stream,
                       part, qsq, out, 250);
  } else {
    hipLaunchKernelGGL(knn_main<125>, dim3(125 * 8), dim3(256), 0, stream,
                       tbp, qb, tsq, part);
    hipLaunchKernelGGL(knn_reduce, dim3(M_QUERY / 256), dim3(256), 0, stream,
                       part, qsq, out, 125);
  }
}